// Round 1
// baseline (513.582 us; speedup 1.0000x reference)
//
#include <hip/hip_runtime.h>

#define NFEAT 128
#define NCLS  64

// ---------------- CSR build ----------------

__global__ void zero_cnt_k(int* __restrict__ cnt, int n) {
    int i = blockIdx.x * blockDim.x + threadIdx.x;
    if (i < n) cnt[i] = 0;
}

__global__ void count_k(const int* __restrict__ col, int E, int* __restrict__ cnt) {
    int e = blockIdx.x * blockDim.x + threadIdx.x;
    if (e < E) atomicAdd(&cnt[col[e]], 1);
}

// block-wise exclusive scan (1024/block) + dinv computation
__global__ void scan1_k(const int* __restrict__ cnt, int* __restrict__ ptrv,
                        int* __restrict__ bsum, float* __restrict__ dinv, int n) {
    __shared__ int s[1024];
    int t = threadIdx.x;
    int i = blockIdx.x * 1024 + t;
    int v = (i < n) ? cnt[i] : 0;
    if (i < n) dinv[i] = rsqrtf((float)(v + 1));  // deg includes self-loop
    s[t] = v;
    for (int off = 1; off < 1024; off <<= 1) {
        __syncthreads();
        int a = (t >= off) ? s[t - off] : 0;
        __syncthreads();
        s[t] += a;
    }
    if (i < n) ptrv[i] = s[t] - v;               // exclusive prefix (local)
    if (t == 1023) bsum[blockIdx.x] = s[1023];   // block total
}

__global__ void scan2_k(int* __restrict__ bsum, int nb) {
    __shared__ int s[128];
    int t = threadIdx.x;
    int v = (t < nb) ? bsum[t] : 0;
    s[t] = v;
    for (int off = 1; off < 128; off <<= 1) {
        __syncthreads();
        int a = (t >= off) ? s[t - off] : 0;
        __syncthreads();
        s[t] += a;
    }
    if (t < nb) bsum[t] = s[t] - v;              // exclusive
}

__global__ void scan3_k(int* __restrict__ ptrv, int* __restrict__ cursor,
                        const int* __restrict__ bsum, int n) {
    int i = blockIdx.x * 1024 + threadIdx.x;
    if (i < n) {
        int p = ptrv[i] + bsum[blockIdx.x];
        ptrv[i] = p;
        cursor[i] = p;
    }
}

__global__ void fill_k(const int* __restrict__ row, const int* __restrict__ col, int E,
                       int* __restrict__ cursor, const float* __restrict__ dinv,
                       int2* __restrict__ csr) {
    int e = blockIdx.x * blockDim.x + threadIdx.x;
    if (e < E) {
        int r = row[e], c = col[e];
        int pos = atomicAdd(&cursor[c], 1);
        csr[pos] = make_int2(r, __float_as_int(dinv[r]));
    }
}

// ---------------- projection: y0 = x @ W^T  (no bias; bias added after hop 2) ----------------
// block = 256 threads, 64 nodes per block. LDS strides padded (132 / 68) so inner-loop
// ds_read_b128 are <=2-way bank conflicts.
__global__ __launch_bounds__(256) void proj_k(const float* __restrict__ x,
                                              const float* __restrict__ W,
                                              float* __restrict__ y, int n) {
    __shared__ float xs[64][132];   // x tile   [node][feat]
    __shared__ float ws[128][68];   // W^T tile [feat][class]
    int t = threadIdx.x;
    int nb = blockIdx.x * 64;

    // stage W transposed: 8192 floats, coalesced float4 reads
    for (int it = 0; it < 8; ++it) {
        int chunk = t + it * 256;            // 0..2047
        int c  = chunk >> 5;                 // class 0..63
        int f4 = (chunk & 31) << 2;          // feat
        float4 wv = *reinterpret_cast<const float4*>(&W[c * NFEAT + f4]);
        ws[f4 + 0][c] = wv.x; ws[f4 + 1][c] = wv.y;
        ws[f4 + 2][c] = wv.z; ws[f4 + 3][c] = wv.w;
    }
    // stage x tile: coalesced float4 reads, float4 LDS writes
    for (int it = 0; it < 8; ++it) {
        int chunk = t + it * 256;            // 0..2047
        int nloc = chunk >> 5;
        int f4   = (chunk & 31) << 2;
        int g = nb + nloc;
        float4 xv = (g < n) ? *reinterpret_cast<const float4*>(&x[(size_t)g * NFEAT + f4])
                            : make_float4(0.f, 0.f, 0.f, 0.f);
        *reinterpret_cast<float4*>(&xs[nloc][f4]) = xv;
    }
    __syncthreads();

    int tc = t & 15;   // class group: classes 4*tc..4*tc+3 (consecutive lanes -> coalesced stores)
    int tn = t >> 4;   // node group:  nodes tn, tn+16, tn+32, tn+48
    float4 acc[4];
#pragma unroll
    for (int i = 0; i < 4; ++i) acc[i] = make_float4(0.f, 0.f, 0.f, 0.f);

    for (int f4 = 0; f4 < NFEAT; f4 += 4) {
        float4 xv[4], wv[4];
#pragma unroll
        for (int i = 0; i < 4; ++i)
            xv[i] = *reinterpret_cast<const float4*>(&xs[tn + 16 * i][f4]);
#pragma unroll
        for (int k = 0; k < 4; ++k)
            wv[k] = *reinterpret_cast<const float4*>(&ws[f4 + k][tc * 4]);
#pragma unroll
        for (int i = 0; i < 4; ++i) {
            acc[i].x += xv[i].x * wv[0].x + xv[i].y * wv[1].x + xv[i].z * wv[2].x + xv[i].w * wv[3].x;
            acc[i].y += xv[i].x * wv[0].y + xv[i].y * wv[1].y + xv[i].z * wv[2].y + xv[i].w * wv[3].y;
            acc[i].z += xv[i].x * wv[0].z + xv[i].y * wv[1].z + xv[i].z * wv[2].z + xv[i].w * wv[3].z;
            acc[i].w += xv[i].x * wv[0].w + xv[i].y * wv[1].w + xv[i].z * wv[2].w + xv[i].w * wv[3].w;
        }
    }
#pragma unroll
    for (int i = 0; i < 4; ++i) {
        int g = nb + tn + 16 * i;
        if (g < n)
            *reinterpret_cast<float4*>(&y[(size_t)g * NCLS + tc * 4]) = acc[i];
    }
}

// ---------------- SpMM hop: yout[i] = dinv[i] * ( sum_j dinv[r_j]*yin[r_j] + dinv[i]*yin[i] ) (+bias)
// one wave per node, lane = class. csr entry = {row, dinv[row]}: one wave-uniform 8B load/neighbor.
template <bool BIAS>
__global__ __launch_bounds__(256) void spmm_k(const float* __restrict__ yin,
                                              float* __restrict__ yout,
                                              const int* __restrict__ ptrv,
                                              const int* __restrict__ cnt,
                                              const float* __restrict__ dinv,
                                              const int2* __restrict__ csr,
                                              const float* __restrict__ bias, int n) {
    int lane = threadIdx.x & 63;
    int wid  = blockIdx.x * 4 + (threadIdx.x >> 6);
    wid = __builtin_amdgcn_readfirstlane(wid);   // force SGPR -> scalar loads below
    if (wid >= n) return;

    float di = dinv[wid];
    int s = ptrv[wid];
    int e = s + cnt[wid];
    float acc = di * yin[(size_t)wid * NCLS + lane];   // self-loop term (weight dinv_i; *dinv_i below)
    for (int j = s; j < e; ++j) {
        int2 rw = csr[j];
        acc = fmaf(__int_as_float(rw.y), yin[(size_t)rw.x * NCLS + lane], acc);
    }
    float o = di * acc;
    if (BIAS) o += bias[lane];
    yout[(size_t)wid * NCLS + lane] = o;
}

// ---------------- launch ----------------

extern "C" void kernel_launch(void* const* d_in, const int* in_sizes, int n_in,
                              void* d_out, int out_size, void* d_ws, size_t ws_size,
                              hipStream_t stream) {
    const float* x  = (const float*)d_in[0];
    const int*   ei = (const int*)d_in[1];
    const float* W  = (const float*)d_in[2];
    const float* b  = (const float*)d_in[3];
    float* out = (float*)d_out;

    const int N = in_sizes[0] / NFEAT;   // 100000
    const int E = in_sizes[1] / 2;       // 1600000
    const int* row = ei;
    const int* col = ei + E;

    // workspace layout (all 4B-aligned; csr is 8B-aligned by construction)
    float* y0     = (float*)d_ws;                 // N*64
    float* y1     = y0 + (size_t)N * NCLS;        // N*64
    int*   cnt    = (int*)(y1 + (size_t)N * NCLS);// N
    int*   ptrv   = cnt + N;                      // N
    int*   cursor = ptrv + N;                     // N
    float* dinv   = (float*)(cursor + N);         // N
    int*   bsum   = (int*)(dinv + N);             // 128
    int2*  csr    = (int2*)(bsum + 128);          // E int2

    size_t needed = ((size_t)N * NCLS * 2 + (size_t)N * 4 + 128) * 4 + (size_t)E * 8;
    if (ws_size < needed) return;  // insufficient scratch: bail (output stays poisoned)

    const int NB = (N + 1023) / 1024;

    zero_cnt_k<<<(N + 255) / 256, 256, 0, stream>>>(cnt, N);
    count_k<<<(E + 255) / 256, 256, 0, stream>>>(col, E, cnt);
    scan1_k<<<NB, 1024, 0, stream>>>(cnt, ptrv, bsum, dinv, N);
    scan2_k<<<1, 128, 0, stream>>>(bsum, NB);
    scan3_k<<<NB, 1024, 0, stream>>>(ptrv, cursor, bsum, N);
    fill_k<<<(E + 255) / 256, 256, 0, stream>>>(row, col, E, cursor, dinv, csr);

    proj_k<<<(N + 63) / 64, 256, 0, stream>>>(x, W, y0, N);

    spmm_k<false><<<(N + 3) / 4, 256, 0, stream>>>(y0, y1, ptrv, cnt, dinv, csr, b, N);
    spmm_k<true ><<<(N + 3) / 4, 256, 0, stream>>>(y1, out, ptrv, cnt, dinv, csr, b, N);
}